// Round 6
// baseline (186.081 us; speedup 1.0000x reference)
//
#include <hip/hip_runtime.h>
#include <hip/hip_bf16.h>

// out = x @ (W + 16*(M@N))^T + b  where M(1024x8), N(8x1024) are folded TT cores.
// Pipeline: prep (build Weff bf16 + cast x->bf16, one launch) ->
// bf16 MFMA GEMM, BK=64, 32x32x16 MFMA (16 instrs/iter vs 32), XOR-swizzled LDS.

#define D_DIM 1024
#define BS_ROWS 16384
#define ALPHA_F 16.0f
#define BM 128
#define BN 128

using bf16   = __bf16;
using bf16x8 = __attribute__((ext_vector_type(8))) __bf16;
using bf16x4 = __attribute__((ext_vector_type(4))) __bf16;
using f32x4  = __attribute__((ext_vector_type(4))) float;
using f32x16 = __attribute__((ext_vector_type(16))) float;

#define GPTR(p) (const __attribute__((address_space(1))) void*)(p)
#define SPTR(p) (__attribute__((address_space(3))) void*)(p)

// ---- Kernel A: fused prep.
// Blocks [0,1024): Weff[o][d] = bf16(W[o][d] + 16*(M@N)[d][o]), o = blockIdx.
// Blocks [1024,9216): cast x chunk to bf16.
__global__ __launch_bounds__(256) void prep_kernel(
    const float* __restrict__ X,
    const float* __restrict__ W,
    const float* __restrict__ c0, const float* __restrict__ c1,
    const float* __restrict__ c2, const float* __restrict__ c3,
    const float* __restrict__ c4, const float* __restrict__ c5,
    bf16* __restrict__ Weff, bf16* __restrict__ Xb)
{
    __shared__ float t2[1024];    // [i2*8+i1][p2] : 128 x 8  (i2 in [0,16))
    __shared__ float Msh[8192];   // [d][p3]
    const int tid = threadIdx.x;

    if (blockIdx.x >= 1024) {
        size_t i = ((size_t)(blockIdx.x - 1024) * 256 + tid) * 8;
        f32x4 a = *(const f32x4*)&X[i];
        f32x4 b = *(const f32x4*)&X[i + 4];
        bf16x8 v;
        v[0] = (bf16)a[0]; v[1] = (bf16)a[1]; v[2] = (bf16)a[2]; v[3] = (bf16)a[3];
        v[4] = (bf16)b[0]; v[5] = (bf16)b[1]; v[6] = (bf16)b[2]; v[7] = (bf16)b[3];
        *(bf16x8*)&Xb[i] = v;
        return;
    }

    const int o = blockIdx.x;
    for (int e = tid; e < 1024; e += 256) {
        int p2 = e & 7, i2i1 = e >> 3;
        int i1 = i2i1 & 7, i2 = i2i1 >> 3;
        float s = 0.f;
        for (int p1 = 0; p1 < 8; ++p1)
            s += c0[i1 * 8 + p1] * c1[p1 * 128 + i2 * 8 + p2];
        t2[e] = s;
    }
    __syncthreads();
    for (int e = tid; e < 8192; e += 256) {
        int p3 = e & 7, d = e >> 3;
        int i1 = d & 7, i2 = (d >> 3) & 15, i3 = d >> 7;
        float s = 0.f;
        for (int p2 = 0; p2 < 8; ++p2)
            s += t2[(i2 * 8 + i1) * 8 + p2] * c2[p2 * 64 + i3 * 8 + p3];
        Msh[e] = s;
    }

    int n1 = o >> 7, nn = o & 127, n2 = nn >> 3, n3 = nn & 7;
    float v[8];
    for (int p4 = 0; p4 < 8; ++p4) {
        float s = 0.f;
        for (int p5 = 0; p5 < 8; ++p5)
            s += c4[p4 * 128 + n2 * 8 + p5] * c5[p5 * 8 + n3];
        v[p4] = s;
    }
    float ncol[8];
    for (int r3 = 0; r3 < 8; ++r3) {
        float s = 0.f;
        for (int p4 = 0; p4 < 8; ++p4)
            s += c3[r3 * 64 + n1 * 8 + p4] * v[p4];
        ncol[r3] = s;
    }
    __syncthreads();

    int d0 = tid * 4;
    f32x4 w = *(const f32x4*)&W[o * D_DIM + d0];
    bf16x4 res;
    for (int k = 0; k < 4; ++k) {
        float acc = 0.f;
        for (int r = 0; r < 8; ++r)
            acc += Msh[(d0 + k) * 8 + r] * ncol[r];
        res[k] = (bf16)(w[k] + ALPHA_F * acc);
    }
    *(bf16x4*)&Weff[o * D_DIM + d0] = res;
}

// ---- Kernel B: 16384x1024x1024 bf16 MFMA GEMM + bias, BK=64, 32x32x16 ------
// LDS rows = 128 B = 8 x 16B chunks; stored chunk = logical ^ (row&7).
// Staging (per wave, 8 issues): lane l covers row w*32+j*8+(l>>3), stored chunk
// l&7 -> loads GLOBAL chunk (l&7)^(l>>3); LDS dst = uniform base + l*16.
// Frag reads (16-lane HW phases): lanes 0-15 = rows 0-15, sc = c^(r&7) covers
// all 8 chunk slots twice -> 2-way (free).
// 32x32x16 layouts: A/B lane holds [mn = lane&31][k = (lane>>5)*8 + i];
// C/D: col = lane&31, row = (reg&3) + 8*(reg>>2) + 4*(lane>>5).
__global__ __launch_bounds__(256) void gemm_bb_kernel(
    const bf16* __restrict__ Xb,
    const bf16* __restrict__ Weff,
    const float* __restrict__ bias,
    float* __restrict__ Out)
{
    __shared__ __align__(16) bf16 As[BM][64];  // 16 KB
    __shared__ __align__(16) bf16 Bs[BN][64];  // 16 KB

    const int tid  = threadIdx.x;
    const int wave = tid >> 6, lane = tid & 63;
    const int mtile = blockIdx.x, ntile = blockIdx.y;
    const int wr = wave >> 1, wc = wave & 1;
    const int l31 = lane & 31, lh = lane >> 5;

    // Staging addresses
    const int srow = wave * 32 + (lane >> 3);
    const int gchunk = (lane & 7) ^ (lane >> 3);
    const bf16* asrc = Xb   + (size_t)(mtile * BM + srow) * D_DIM + gchunk * 8;
    const bf16* bsrc = Weff + (size_t)(ntile * BN + srow) * D_DIM + gchunk * 8;
    char* abase = (char*)&As[0][0] + wave * 4096;
    char* bbase = (char*)&Bs[0][0] + wave * 4096;

    // Fragment row indices (row&7 = lane&7 for both A and B frags)
    const int arow0 = wr * 64 + l31;        // i adds 32
    const int brow0 = wc * 64 + l31;        // j adds 32
    const int rsw = lane & 7;               // row&7 (same for +32 offsets)

    f32x16 acc[2][2];
    for (int i = 0; i < 2; ++i)
        for (int j = 0; j < 2; ++j)
            for (int r = 0; r < 16; ++r) acc[i][j][r] = 0.f;

    for (int kt = 0; kt < D_DIM / 64; ++kt) {
        const int ko = kt * 64;
        for (int j = 0; j < 4; ++j) {
            __builtin_amdgcn_global_load_lds(GPTR(asrc + (size_t)j * 8 * D_DIM + ko),
                                             SPTR(abase + j * 1024), 16, 0, 0);
            __builtin_amdgcn_global_load_lds(GPTR(bsrc + (size_t)j * 8 * D_DIM + ko),
                                             SPTR(bbase + j * 1024), 16, 0, 0);
        }

        __syncthreads();

        for (int ks = 0; ks < 4; ++ks) {                 // K = 16 per step
            const int lc = ks * 2 + lh;                  // logical 16B chunk
            const int sc = (lc ^ rsw) * 8;               // stored chunk (elems)
            bf16x8 af[2], bfr[2];
            for (int i = 0; i < 2; ++i)
                af[i] = *(const bf16x8*)&As[arow0 + i * 32][sc];
            for (int j = 0; j < 2; ++j)
                bfr[j] = *(const bf16x8*)&Bs[brow0 + j * 32][sc];
            for (int i = 0; i < 2; ++i)
                for (int j = 0; j < 2; ++j)
                    acc[i][j] = __builtin_amdgcn_mfma_f32_32x32x16_bf16(
                        af[i], bfr[j], acc[i][j], 0, 0, 0);
        }

        __syncthreads();
    }

    // Epilogue: col = lane&31, row = (reg&3) + 8*(reg>>2) + 4*lh
    float bj[2];
    for (int j = 0; j < 2; ++j)
        bj[j] = bias[ntile * BN + wc * 64 + j * 32 + l31];
    for (int i = 0; i < 2; ++i) {
        int rowbase = mtile * BM + wr * 64 + i * 32 + 4 * lh;
        for (int reg = 0; reg < 16; ++reg) {
            int row = rowbase + (reg & 3) + 8 * (reg >> 2);
            float* orow = Out + (size_t)row * D_DIM + ntile * BN + wc * 64 + l31;
            for (int j = 0; j < 2; ++j)
                orow[j * 32] = acc[i][j][reg] + bj[j];
        }
    }
}

// ---- Fallback GEMM (fp32 A staged via VALU convert) — used if ws too small --
__global__ __launch_bounds__(256) void gemm_bias_kernel(
    const float* __restrict__ X,
    const bf16* __restrict__ Weff,
    const float* __restrict__ bias,
    float* __restrict__ Out)
{
    __shared__ __align__(16) bf16 As[BM][32];
    __shared__ __align__(16) bf16 Bs[BN][32];

    const int tid  = threadIdx.x;
    const int wave = tid >> 6, lane = tid & 63;
    const int mtile = blockIdx.x, ntile = blockIdx.y;
    const int wr = wave >> 1, wc = wave & 1;
    const int l15 = lane & 15, quad = lane >> 4;

    const int ar = tid >> 1, ah = tid & 1;
    const float* xsrc = X + (size_t)(mtile * BM + ar) * D_DIM + ah * 16;
    bf16* adst = &As[ar][ah * 16];

    const bf16* bsrc0 = Weff + (size_t)(ntile * BN + wave * 32 + (lane >> 2)) * D_DIM
                        + (lane & 3) * 8;
    const bf16* bsrc1 = bsrc0 + 16 * D_DIM;
    char* bbase = (char*)&Bs[0][0];
    void* bdst0 = bbase + wave * 2048;
    void* bdst1 = bbase + wave * 2048 + 1024;

    f32x4 acc[4][4];
    for (int i = 0; i < 4; ++i)
        for (int j = 0; j < 4; ++j)
            for (int r = 0; r < 4; ++r) acc[i][j][r] = 0.f;

    for (int kt = 0; kt < D_DIM / 32; ++kt) {
        __builtin_amdgcn_global_load_lds(GPTR(bsrc0 + kt * 32), SPTR(bdst0), 16, 0, 0);
        __builtin_amdgcn_global_load_lds(GPTR(bsrc1 + kt * 32), SPTR(bdst1), 16, 0, 0);

        const f32x4* xp = (const f32x4*)(xsrc + kt * 32);
        f32x4 f0 = xp[0], f1 = xp[1], f2 = xp[2], f3 = xp[3];
        bf16x8 p0, p1;
        p0[0] = (bf16)f0[0]; p0[1] = (bf16)f0[1]; p0[2] = (bf16)f0[2]; p0[3] = (bf16)f0[3];
        p0[4] = (bf16)f1[0]; p0[5] = (bf16)f1[1]; p0[6] = (bf16)f1[2]; p0[7] = (bf16)f1[3];
        p1[0] = (bf16)f2[0]; p1[1] = (bf16)f2[1]; p1[2] = (bf16)f2[2]; p1[3] = (bf16)f2[3];
        p1[4] = (bf16)f3[0]; p1[5] = (bf16)f3[1]; p1[6] = (bf16)f3[2]; p1[7] = (bf16)f3[3];
        *(bf16x8*)adst = p0;
        *(bf16x8*)(adst + 8) = p1;

        __syncthreads();

        bf16x8 af[4], bfr[4];
        for (int i = 0; i < 4; ++i)
            af[i] = *(const bf16x8*)&As[wr * 64 + i * 16 + l15][quad * 8];
        for (int j = 0; j < 4; ++j)
            bfr[j] = *(const bf16x8*)&Bs[wc * 64 + j * 16 + l15][quad * 8];
        for (int i = 0; i < 4; ++i)
            for (int j = 0; j < 4; ++j)
                acc[i][j] = __builtin_amdgcn_mfma_f32_16x16x32_bf16(
                    af[i], bfr[j], acc[i][j], 0, 0, 0);

        __syncthreads();
    }

    float bj[4];
    for (int j = 0; j < 4; ++j)
        bj[j] = bias[ntile * BN + wc * 64 + j * 16 + l15];
    for (int i = 0; i < 4; ++i) {
        int row0 = mtile * BM + wr * 64 + i * 16 + quad * 4;
        for (int r = 0; r < 4; ++r) {
            float* orow = Out + (size_t)(row0 + r) * D_DIM + ntile * BN + wc * 64 + l15;
            for (int j = 0; j < 4; ++j)
                orow[j * 16] = acc[i][j][r] + bj[j];
        }
    }
}

// Standalone Weff builder for fallback path
__global__ __launch_bounds__(256) void build_weff_fused_kernel(
    const float* __restrict__ W,
    const float* __restrict__ c0, const float* __restrict__ c1,
    const float* __restrict__ c2, const float* __restrict__ c3,
    const float* __restrict__ c4, const float* __restrict__ c5,
    bf16* __restrict__ Weff)
{
    __shared__ float t2[1024];
    __shared__ float Msh[8192];
    const int tid = threadIdx.x;
    const int o = blockIdx.x;

    for (int e = tid; e < 1024; e += 256) {
        int p2 = e & 7, i2i1 = e >> 3;
        int i1 = i2i1 & 7, i2 = i2i1 >> 3;
        float s = 0.f;
        for (int p1 = 0; p1 < 8; ++p1)
            s += c0[i1 * 8 + p1] * c1[p1 * 128 + i2 * 8 + p2];
        t2[e] = s;
    }
    __syncthreads();
    for (int e = tid; e < 8192; e += 256) {
        int p3 = e & 7, d = e >> 3;
        int i1 = d & 7, i2 = (d >> 3) & 15, i3 = d >> 7;
        float s = 0.f;
        for (int p2 = 0; p2 < 8; ++p2)
            s += t2[(i2 * 8 + i1) * 8 + p2] * c2[p2 * 64 + i3 * 8 + p3];
        Msh[e] = s;
    }
    int n1 = o >> 7, nn = o & 127, n2 = nn >> 3, n3 = nn & 7;
    float v[8];
    for (int p4 = 0; p4 < 8; ++p4) {
        float s = 0.f;
        for (int p5 = 0; p5 < 8; ++p5)
            s += c4[p4 * 128 + n2 * 8 + p5] * c5[p5 * 8 + n3];
        v[p4] = s;
    }
    float ncol[8];
    for (int r3 = 0; r3 < 8; ++r3) {
        float s = 0.f;
        for (int p4 = 0; p4 < 8; ++p4)
            s += c3[r3 * 64 + n1 * 8 + p4] * v[p4];
        ncol[r3] = s;
    }
    __syncthreads();

    int d0 = tid * 4;
    f32x4 w = *(const f32x4*)&W[o * D_DIM + d0];
    bf16x4 res;
    for (int k = 0; k < 4; ++k) {
        float acc = 0.f;
        for (int r = 0; r < 8; ++r)
            acc += Msh[(d0 + k) * 8 + r] * ncol[r];
        res[k] = (bf16)(w[k] + ALPHA_F * acc);
    }
    *(bf16x4*)&Weff[o * D_DIM + d0] = res;
}

extern "C" void kernel_launch(void* const* d_in, const int* in_sizes, int n_in,
                              void* d_out, int out_size, void* d_ws, size_t ws_size,
                              hipStream_t stream) {
    const float* x  = (const float*)d_in[0];
    const float* W  = (const float*)d_in[1];
    const float* b  = (const float*)d_in[2];
    const float* c0 = (const float*)d_in[3];
    const float* c1 = (const float*)d_in[4];
    const float* c2 = (const float*)d_in[5];
    const float* c3 = (const float*)d_in[6];
    const float* c4 = (const float*)d_in[7];
    const float* c5 = (const float*)d_in[8];
    float* out = (float*)d_out;

    // Workspace: Weff bf16 2MB @0 | Xb 32MB @4MB
    char* ws = (char*)d_ws;
    bf16* Weff = (bf16*)ws;
    bf16* Xb   = (bf16*)(ws + 4u * 1024u * 1024u);
    const size_t need = 4u * 1024u * 1024u + (size_t)BS_ROWS * D_DIM * 2u;

    dim3 grid(BS_ROWS / BM, D_DIM / BN);
    if (ws_size >= need) {
        prep_kernel<<<1024 + 8192, 256, 0, stream>>>(x, W, c0, c1, c2, c3, c4, c5,
                                                     Weff, Xb);
        gemm_bb_kernel<<<grid, 256, 0, stream>>>(Xb, Weff, b, out);
    } else {
        build_weff_fused_kernel<<<D_DIM, 256, 0, stream>>>(W, c0, c1, c2, c3, c4, c5, Weff);
        gemm_bias_kernel<<<grid, 256, 0, stream>>>(x, Weff, b, out);
    }
}